// Round 1
// baseline (125.291 us; speedup 1.0000x reference)
//
#include <hip/hip_runtime.h>
#include <hip/hip_bf16.h>

// Batched matmul: [24, 1024, 64] (fp32) x [24, 64, 1024] (fp32) -> [24, 1024, 1024] (fp32)
// Compute in bf16 MFMA (threshold is bf16-floor), output-store-bound (~100 MB writes).

#define MM 1024
#define NN 1024
#define KK 64

typedef __attribute__((ext_vector_type(4))) float  float4v;
typedef __attribute__((ext_vector_type(4))) short  short4v;
typedef __attribute__((ext_vector_type(8))) short  bf16x8;    // 8 bf16 in 4 VGPRs
typedef __attribute__((ext_vector_type(16))) float floatx16;  // 32x32 MFMA acc

// fp32 -> bf16 bits, round-to-nearest-even (inputs are finite; no NaN handling needed)
__device__ __forceinline__ short f2bs(float f) {
    union { float f; unsigned u; } in;
    in.f = f;
    unsigned u = in.u;
    unsigned r = (u + 0x7FFFu + ((u >> 16) & 1u)) >> 16;
    return (short)r;
}

__global__ __launch_bounds__(256) void bmm_bf16_kernel(const float* __restrict__ A,
                                                       const float* __restrict__ B,
                                                       float* __restrict__ C) {
    // LDS in MFMA-fragment order: block (tile, ks) holds 64 lanes x 8 bf16 contiguously.
    // A frag (32x32x16): lane = (m&31) + ((k>>3)&1)*32, elems j = k&7 (k within 16-step)
    // B frag:            lane = (n&31) + ((k>>3)&1)*32, elems j = k&7
    __shared__ __align__(16) short a_sh[16 * 512];  // (mt*4+ks)*512 + lane*8 + j
    __shared__ __align__(16) short b_sh[16 * 512];  // (nt*4+ks)*512 + lane*8 + j

    const int tid = threadIdx.x;
    const int bx = blockIdx.x;   // n-tile 0..7
    const int by = blockIdx.y;   // m-tile 0..7
    const int bh = blockIdx.z;   // batch*head 0..23

    const int m0 = by * 128;
    const int n0 = bx * 128;

    const float* Ab = A + (size_t)bh * (MM * KK) + (size_t)m0 * KK;  // contiguous 128x64
    const float* Bb = B + (size_t)bh * (KK * NN) + n0;               // [k][n], row stride NN

    // ---- stage A: coalesced float4 reads, bf16 pack, ds_write_b64 ----
    {
        const float4v* A4 = (const float4v*)Ab;
        #pragma unroll
        for (int i = 0; i < 8; ++i) {
            int f4 = tid + i * 256;          // 0..2047
            float4v v = A4[f4];
            int m  = f4 >> 4;                // 0..127
            int k  = (f4 & 15) << 2;         // 0..60, step 4 (stays within one j-group)
            int mt = m >> 5;
            int ks = k >> 4;
            int q  = (k >> 3) & 1;
            int j0 = k & 7;                  // 0 or 4
            int lane = (m & 31) + (q << 5);
            int dst = ((mt * 4 + ks) * 64 + lane) * 8 + j0;
            short4v s;
            s.x = f2bs(v.x); s.y = f2bs(v.y); s.z = f2bs(v.z); s.w = f2bs(v.w);
            *(short4v*)&a_sh[dst] = s;
        }
    }

    // ---- stage B: per-k coalesced dword reads (each thread gathers 4 consecutive k
    //      for one n), bf16 pack, ds_write_b64 ----
    {
        int n  = tid & 127;
        int kh = tid >> 7;                   // 0..1
        int nt = n >> 5;
        int lanebase = n & 31;
        #pragma unroll
        for (int s = 0; s < 8; ++s) {
            int k0 = kh * 4 + s * 8;         // {0,4} + 8s -> covers 0,4,...,60
            float v0 = Bb[(size_t)(k0 + 0) * NN + n];
            float v1 = Bb[(size_t)(k0 + 1) * NN + n];
            float v2 = Bb[(size_t)(k0 + 2) * NN + n];
            float v3 = Bb[(size_t)(k0 + 3) * NN + n];
            int ks = k0 >> 4;
            int q  = (k0 >> 3) & 1;
            int j0 = k0 & 7;
            int lane = lanebase + (q << 5);
            int dst = ((nt * 4 + ks) * 64 + lane) * 8 + j0;
            short4v sv;
            sv.x = f2bs(v0); sv.y = f2bs(v1); sv.z = f2bs(v2); sv.w = f2bs(v3);
            *(short4v*)&b_sh[dst] = sv;
        }
    }

    __syncthreads();

    // ---- compute: each wave does a 64x64 region = 2x2 of 32x32 tiles, K=64 in 4 steps ----
    const int w    = tid >> 6;
    const int lane = tid & 63;
    const int wm   = (w >> 1) * 2;   // base 32-tile index in m (0 or 2)
    const int wn   = (w & 1) * 2;    // base 32-tile index in n (0 or 2)

    floatx16 acc[2][2];
    #pragma unroll
    for (int mi = 0; mi < 2; ++mi)
        #pragma unroll
        for (int ni = 0; ni < 2; ++ni)
            #pragma unroll
            for (int r = 0; r < 16; ++r)
                acc[mi][ni][r] = 0.0f;

    #pragma unroll
    for (int ks = 0; ks < 4; ++ks) {
        bf16x8 a0 = *(const bf16x8*)&a_sh[((wm + 0) * 4 + ks) * 512 + lane * 8];
        bf16x8 a1 = *(const bf16x8*)&a_sh[((wm + 1) * 4 + ks) * 512 + lane * 8];
        bf16x8 b0 = *(const bf16x8*)&b_sh[((wn + 0) * 4 + ks) * 512 + lane * 8];
        bf16x8 b1 = *(const bf16x8*)&b_sh[((wn + 1) * 4 + ks) * 512 + lane * 8];
        acc[0][0] = __builtin_amdgcn_mfma_f32_32x32x16_bf16(a0, b0, acc[0][0], 0, 0, 0);
        acc[0][1] = __builtin_amdgcn_mfma_f32_32x32x16_bf16(a0, b1, acc[0][1], 0, 0, 0);
        acc[1][0] = __builtin_amdgcn_mfma_f32_32x32x16_bf16(a1, b0, acc[1][0], 0, 0, 0);
        acc[1][1] = __builtin_amdgcn_mfma_f32_32x32x16_bf16(a1, b1, acc[1][1], 0, 0, 0);
    }

    // ---- store: C/D layout col=lane&31, row=(r&3)+8*(r>>2)+4*(lane>>5)
    //      per store instr: 2 x 128-B contiguous segments -> fully coalesced ----
    float* Cb = C + (size_t)bh * (MM * NN) + (size_t)m0 * NN + n0;
    const int cc    = lane & 31;
    const int rbase = (lane >> 5) * 4;

    #pragma unroll
    for (int mi = 0; mi < 2; ++mi) {
        #pragma unroll
        for (int ni = 0; ni < 2; ++ni) {
            float* Ct = Cb + (size_t)((wm + mi) * 32) * NN + (wn + ni) * 32 + cc;
            #pragma unroll
            for (int r = 0; r < 16; ++r) {
                int row = rbase + (r & 3) + ((r >> 2) * 8);
                Ct[(size_t)row * NN] = acc[mi][ni][r];
            }
        }
    }
}

extern "C" void kernel_launch(void* const* d_in, const int* in_sizes, int n_in,
                              void* d_out, int out_size, void* d_ws, size_t ws_size,
                              hipStream_t stream) {
    const float* x1 = (const float*)d_in[0];   // [2,12,1024,64]
    const float* x2 = (const float*)d_in[1];   // [2,12,64,1024]
    // d_in[2], d_in[3] (clip_val1/2) unused in forward
    float* out = (float*)d_out;                // [2,12,1024,1024] fp32

    dim3 grid(8, 8, 24);
    dim3 block(256);
    hipLaunchKernelGGL(bmm_bf16_kernel, grid, block, 0, stream, x1, x2, out);
}